// Round 13
// baseline (256.432 us; speedup 1.0000x reference)
//
#include <hip/hip_runtime.h>
#include <hip/hip_bf16.h>
#include <stdint.h>

#define B_ 4
#define T_ 2048
#define D_ 1024
#define H_ 16
#define DK_ 64
#define M_ (B_*T_)   // 8192

typedef __attribute__((ext_vector_type(8))) short bf16x8;
typedef __attribute__((ext_vector_type(4))) short bf16x4;
typedef __attribute__((ext_vector_type(4))) float f32x4;
typedef __hip_bfloat16 bf16;

__device__ __forceinline__ void gld_lds16(const bf16* g, bf16* l) {
  __builtin_amdgcn_global_load_lds((const __attribute__((address_space(1))) void*)g,
                                   (__attribute__((address_space(3))) void*)l,
                                   16, 0, 0);
}

__device__ __forceinline__ short bfbits(float f) {
  union { bf16 h; short s; } u; u.h = __float2bfloat16(f); return u.s;
}

// ---------------------------------------------------------------------------
// fused fp32 -> bf16 convert of all 7 tensors (round-8 exact)
// ---------------------------------------------------------------------------
__global__ __launch_bounds__(256) void cvt_all(
    const float* __restrict__ q, const float* __restrict__ k, const float* __restrict__ v,
    const float* __restrict__ wq, const float* __restrict__ wk,
    const float* __restrict__ wv, const float* __restrict__ wo,
    bf16* __restrict__ qb, bf16* __restrict__ kb, bf16* __restrict__ vb,
    bf16* __restrict__ wqb, bf16* __restrict__ wkb,
    bf16* __restrict__ wvb, bf16* __restrict__ wob) {
  int gid = blockIdx.x * 256 + threadIdx.x;   // 0 .. 7340031
  const float* src; bf16* dst; int off;
  if (gid < 6291456) {
    int s = gid >> 21; off = gid & 2097151;
    src = (s == 0) ? q : (s == 1) ? k : v;
    dst = (s == 0) ? qb : (s == 1) ? kb : vb;
  } else {
    int g2 = gid - 6291456;
    int s = g2 >> 18; off = g2 & 262143;
    src = (s == 0) ? wq : (s == 1) ? wk : (s == 2) ? wv : wo;
    dst = (s == 0) ? wqb : (s == 1) ? wkb : (s == 2) ? wvb : wob;
  }
  float4 val = reinterpret_cast<const float4*>(src)[off];
  union { ushort4 u; bf16 h[4]; } o;
  o.h[0] = __float2bfloat16(val.x);
  o.h[1] = __float2bfloat16(val.y);
  o.h[2] = __float2bfloat16(val.z);
  o.h[3] = __float2bfloat16(val.w);
  reinterpret_cast<ushort4*>(dst)[off] = o.u;
}

// ---------------------------------------------------------------------------
// Fused QKV projection GEMM v2: 256x128 tile, 512 threads, 3-slot LDS
// rotation with counted vmcnt (T3+T4). Group t reads slot t%3 (K-tile t)
// while staging K-tile t+2 into slot (t+2)%3 (read-finished in group t-1).
// 4 phases per K-tile: {1 half-tile stage || 2 A-frag ds_read -> s_barrier ->
// 8 MFMA -> s_barrier}; B-frags read once per tile into registers.
// Group-end wait = vmcnt(6) (6 loads/thread/tile in flight), never 0 until
// the epilogue tiles. Raw s_barrier (no __syncthreads vmcnt(0) drain).
// ---------------------------------------------------------------------------
__global__ __launch_bounds__(512) void proj_qkv(
    const bf16* __restrict__ qb, const bf16* __restrict__ kb, const bf16* __restrict__ vb,
    const bf16* __restrict__ Wqb, const bf16* __restrict__ Wkb, const bf16* __restrict__ Wvb,
    const float* __restrict__ bq, const float* __restrict__ bk, const float* __restrict__ bv,
    bf16* __restrict__ Qh, bf16* __restrict__ Kh, bf16* __restrict__ Vt) {
  constexpr int K = 1024;
  constexpr int BK = 64;
  constexpr int NT = 16;                       // K / BK
  __shared__ __align__(16) bf16 As[3][2][128 * 64];   // 96 KB: slot, half
  __shared__ __align__(16) bf16 Bs[3][128 * 64];      // 48 KB

  const int z = blockIdx.z;
  const bool vt = (z == 2);
  const bf16* A  = (z == 0) ? qb : (z == 1) ? kb : Wvb;
  const bf16* Bm = (z == 0) ? Wqb : (z == 1) ? Wkb : vb;
  const float* bias = (z == 0) ? bq : (z == 1) ? bk : bv;
  bf16* out = (z == 0) ? Qh : (z == 1) ? Kh : Vt;
  const float scale = (z == 0) ? 0.125f * 1.4426950408889634f : 1.0f;

  int bm, bn;
  if (vt) { int flat = blockIdx.x + 32 * blockIdx.y; bm = flat >> 6; bn = flat & 63; }
  else    { bm = blockIdx.x; bn = blockIdx.y; }

  const int tid = threadIdx.x;
  const int w = tid >> 6, l = tid & 63;
  const int wm = w >> 1, wn = w & 1;           // 4M x 2N wave grid
  const int lr = l & 15, lk = l >> 4;

  f32x4 acc[4][4] = {};
  bf16x8 bfrag[4][2];

  // stage helpers: A half h (128x64, 2 loads/thread), B part (64 rows, 1 load)
  auto stgA = [&](int t2, int sl, int h) {
#pragma unroll
    for (int i = 0; i < 2; ++i) {
      int p = i * 512 + tid;
      int row = p >> 3;
      int so = (p & 7) ^ (row & 7);
      gld_lds16(A + (size_t)(bm * 256 + h * 128 + row) * K + t2 * BK + so * 8,
                &As[sl][h][p * 8]);
    }
  };
  auto stgB = [&](int t2, int sl, int part) {
    int p = part * 512 + tid;
    int row = p >> 3;
    int so = (p & 7) ^ (row & 7);
    gld_lds16(Bm + (size_t)(bn * 128 + row) * K + t2 * BK + so * 8,
              &Bs[sl][p * 8]);
  };

  // prologue: tiles 0,1 -> slots 0,1 (12 loads); drain tile 0, keep tile 1
  stgA(0, 0, 0); stgA(0, 0, 1); stgB(0, 0, 0); stgB(0, 0, 1);
  stgA(1, 1, 0); stgA(1, 1, 1); stgB(1, 1, 0); stgB(1, 1, 1);
  asm volatile("s_waitcnt vmcnt(6)" ::: "memory");
  asm volatile("s_barrier" ::: "memory");

  int sl0 = 0;
#pragma unroll 1
  for (int t = 0; t < NT; ++t) {
    const int sl2 = (sl0 + 2 >= 3) ? sl0 - 1 : sl0 + 2;
    const bool pre = (t + 2 < NT);

    auto mfma_row = [&](int m) {
      int lrow = (wm & 1) * 64 + m * 16 + lr;
      int a0s = lk ^ (lrow & 7);
      int a1s = (4 + lk) ^ (lrow & 7);
      bf16x8 a0 = *reinterpret_cast<const bf16x8*>(&As[sl0][wm >> 1][lrow * 64 + a0s * 8]);
      bf16x8 a1 = *reinterpret_cast<const bf16x8*>(&As[sl0][wm >> 1][lrow * 64 + a1s * 8]);
      asm volatile("s_barrier" ::: "memory");
      __builtin_amdgcn_s_setprio(1);
#pragma unroll
      for (int n = 0; n < 4; ++n)
        acc[m][n] = __builtin_amdgcn_mfma_f32_16x16x32_bf16(a0, bfrag[n][0], acc[m][n], 0, 0, 0);
#pragma unroll
      for (int n = 0; n < 4; ++n)
        acc[m][n] = __builtin_amdgcn_mfma_f32_16x16x32_bf16(a1, bfrag[n][1], acc[m][n], 0, 0, 0);
      __builtin_amdgcn_s_setprio(0);
    };

    // ---- phase 0: stage A(t+2) h0; read B-frags (once per tile) ----
    if (pre) stgA(t + 2, sl2, 0);
#pragma unroll
    for (int n = 0; n < 4; ++n) {
      int brow = wn * 64 + n * 16 + lr;
      int b0s = lk ^ (brow & 7);
      int b1s = (4 + lk) ^ (brow & 7);
      bfrag[n][0] = *reinterpret_cast<const bf16x8*>(&Bs[sl0][brow * 64 + b0s * 8]);
      bfrag[n][1] = *reinterpret_cast<const bf16x8*>(&Bs[sl0][brow * 64 + b1s * 8]);
    }
    mfma_row(0);
    asm volatile("s_barrier" ::: "memory");

    // ---- phase 1: stage A(t+2) h1 ----
    if (pre) stgA(t + 2, sl2, 1);
    mfma_row(1);
    asm volatile("s_barrier" ::: "memory");

    // ---- phase 2: stage B(t+2) part0 ----
    if (pre) stgB(t + 2, sl2, 0);
    mfma_row(2);
    asm volatile("s_barrier" ::: "memory");

    // ---- phase 3: stage B(t+2) part1; group-end counted wait ----
    if (pre) stgB(t + 2, sl2, 1);
    mfma_row(3);
    if (t + 3 < NT) asm volatile("s_waitcnt vmcnt(6)" ::: "memory");
    else            asm volatile("s_waitcnt vmcnt(0)" ::: "memory");
    asm volatile("s_barrier" ::: "memory");

    sl0 = (sl0 + 1 >= 3) ? 0 : sl0 + 1;
  }

  const int crow0 = bm * 256 + wm * 64;
  const int ccol0 = bn * 128 + wn * 64;
#pragma unroll
  for (int m = 0; m < 4; ++m) {
#pragma unroll
    for (int n = 0; n < 4; ++n) {
#pragma unroll
      for (int r = 0; r < 4; ++r) {
        const int row = crow0 + m * 16 + lk * 4 + r;
        const int col = ccol0 + n * 16 + lr;
        if (!vt) {
          float vv = (acc[m][n][r] + bias[col]) * scale;
          size_t idx = (((size_t)(row >> 11) * H_ + (col >> 6)) * T_ + (row & (T_ - 1))) * DK_ + (col & (DK_ - 1));
          out[idx] = __float2bfloat16(vv);
        } else {
          float vv = acc[m][n][r] + bias[row];
          size_t idx = (size_t)(col >> 11) * ((size_t)H_ * DK_ * T_) + (size_t)row * T_ + (col & (T_ - 1));
          out[idx] = __float2bfloat16(vv);
        }
      }
    }
  }
}

// ---------------------------------------------------------------------------
// Output GEMM (fp32 out), 256x128 tile, 512 threads (round-8 exact)
// ---------------------------------------------------------------------------
__global__ __launch_bounds__(512) void gemm_out(const bf16* __restrict__ A,
                                                const bf16* __restrict__ Bm,
                                                const float* __restrict__ bias,
                                                float* __restrict__ Cout) {
  constexpr int K = 1024;
  constexpr int BK = 64;
  __shared__ __align__(16) bf16 As[256 * BK];
  __shared__ __align__(16) bf16 Bs[128 * BK];

  const int bm = blockIdx.x;
  const int bn = blockIdx.y;
  const int tid = threadIdx.x;
  const int w = tid >> 6, l = tid & 63;
  const int wm = w >> 1, wn = w & 1;
  const int lr = l & 15, lk = l >> 4;

  f32x4 acc[4][4] = {};

  for (int k0 = 0; k0 < K; k0 += BK) {
#pragma unroll
    for (int i = 0; i < 4; ++i) {
      int p = i * 512 + tid;
      int row = p >> 3;
      int so = (p & 7) ^ (row & 7);
      gld_lds16(A + (size_t)(bm * 256 + row) * K + k0 + so * 8, &As[p * 8]);
    }
#pragma unroll
    for (int i = 0; i < 2; ++i) {
      int p = i * 512 + tid;
      int row = p >> 3;
      int so = (p & 7) ^ (row & 7);
      gld_lds16(Bm + (size_t)(bn * 128 + row) * K + k0 + so * 8, &Bs[p * 8]);
    }
    __syncthreads();

#pragma unroll
    for (int kk = 0; kk < 2; ++kk) {
      bf16x8 af[4], bfr[4];
#pragma unroll
      for (int m = 0; m < 4; ++m) {
        int row = wm * 64 + m * 16 + lr;
        int slot = (kk * 4 + lk) ^ (row & 7);
        af[m] = *reinterpret_cast<const bf16x8*>(&As[row * BK + slot * 8]);
      }
#pragma unroll
      for (int n = 0; n < 4; ++n) {
        int row = wn * 64 + n * 16 + lr;
        int slot = (kk * 4 + lk) ^ (row & 7);
        bfr[n] = *reinterpret_cast<const bf16x8*>(&Bs[row * BK + slot * 8]);
      }
#pragma unroll
      for (int m = 0; m < 4; ++m)
#pragma unroll
        for (int n = 0; n < 4; ++n)
          acc[m][n] = __builtin_amdgcn_mfma_f32_16x16x32_bf16(af[m], bfr[n], acc[m][n], 0, 0, 0);
    }
    __syncthreads();
  }

  const int crow0 = bm * 256 + wm * 64;
  const int ccol0 = bn * 128 + wn * 64;
#pragma unroll
  for (int m = 0; m < 4; ++m) {
#pragma unroll
    for (int n = 0; n < 4; ++n) {
#pragma unroll
      for (int r = 0; r < 4; ++r) {
        const int row = crow0 + m * 16 + lk * 4 + r;
        const int col = ccol0 + n * 16 + lr;
        Cout[(size_t)row * D_ + col] = acc[m][n][r] + bias[col];
      }
    }
  }
}

// ---------------------------------------------------------------------------
// Causal flash attention (round-12 exact): 7 blocks/CU, KVBLK=32,
// fixed-shift softmax, packed V, heavy-first single-task blocks.
// ---------------------------------------------------------------------------
__global__ __launch_bounds__(256, 7) void attn_fwd(const bf16* __restrict__ Qh,
                                                   const bf16* __restrict__ Kh,
                                                   const bf16* __restrict__ Vt,
                                                   bf16* __restrict__ ctx) {
  __shared__ __align__(16) bf16 Kbuf[2][32 * 64];
  __shared__ __align__(16) bf16 Vbuf[2][32 * 64];
  __shared__ __align__(16) char Ps[4][16 * 80];

  const int tid = threadIdx.x, w = tid >> 6, l = tid & 63;
  const int lr = l & 15, lk = l >> 4;
  const int bid = blockIdx.x;
  const int head = bid & 63;
  const int t = 31 - (bid >> 6);
  char* Pw = &Ps[w][0];

  const bf16* Qb = Qh + (size_t)head * T_ * DK_;
  const bf16* Kb = Kh + (size_t)head * T_ * DK_;
  const bf16* Vb = Vt + (size_t)head * DK_ * T_;
  const int bb = head >> 4, hh = head & 15;

  const int r0 = t * 64;
  const int nt32 = 2 * (t + 1);
  const int qrow = r0 + w * 16 + lr;
  const int jd = (r0 + w * 16) >> 5;

  const bf16* qp = Qb + (size_t)qrow * DK_ + lk * 8;
  bf16x8 qf0 = *reinterpret_cast<const bf16x8*>(qp);
  bf16x8 qf1 = *reinterpret_cast<const bf16x8*>(qp + 32);

  f32x4 oacc[4] = {};
  float srow = 0.f;

  {
    int p = tid;
    int krow = p >> 3;
    int kso = (p & 7) ^ (krow & 7);
    gld_lds16(Kb + (size_t)krow * DK_ + kso * 8, &Kbuf[0][p * 8]);
    int vrow = p >> 3;
    int u = (p & 7) ^ (vrow & 7);
    int dk = vrow * 2 + (u >> 2);
    gld_lds16(Vb + (size_t)dk * T_ + (u & 3) * 8, &Vbuf[0][p * 8]);
  }
  __syncthreads();

  int buf = 0;
#pragma unroll 1
  for (int j = 0; j < nt32; ++j) {
    if (j + 1 < nt32) {
      const int k0n = (j + 1) * 32;
      int p = tid;
      int krow = p >> 3;
      int kso = (p & 7) ^ (krow & 7);
      gld_lds16(Kb + (size_t)(k0n + krow) * DK_ + kso * 8, &Kbuf[buf ^ 1][p * 8]);
      int vrow = p >> 3;
      int u = (p & 7) ^ (vrow & 7);
      int dk = vrow * 2 + (u >> 2);
      gld_lds16(Vb + (size_t)dk * T_ + k0n + (u & 3) * 8, &Vbuf[buf ^ 1][p * 8]);
    }

    if (j <= jd) {
      f32x4 sacc[2] = {};
      __builtin_amdgcn_s_setprio(1);
#pragma unroll
      for (int n = 0; n < 2; ++n) {
        int row = n * 16 + lr;
        int s0 = lk ^ (row & 7);
        int s1 = (4 + lk) ^ (row & 7);
        bf16x8 kf0 = *reinterpret_cast<const bf16x8*>(&Kbuf[buf][row * 64 + s0 * 8]);
        bf16x8 kf1 = *reinterpret_cast<const bf16x8*>(&Kbuf[buf][row * 64 + s1 * 8]);
        sacc[n] = __builtin_amdgcn_mfma_f32_16x16x32_bf16(kf0, qf0, sacc[n], 0, 0, 0);
        sacc[n] = __builtin_amdgcn_mfma_f32_16x16x32_bf16(kf1, qf1, sacc[n], 0, 0, 0);
      }
      __builtin_amdgcn_s_setprio(0);

      if (j == jd) {
#pragma unroll
        for (int n = 0; n < 2; ++n)
#pragma unroll
          for (int r = 0; r < 4; ++r)
            if (j * 32 + n * 16 + lk * 4 + r > qrow) sacc[n][r] = -1e30f;
      }

      float ts = 0.f;
#pragma unroll
      for (int n = 0; n < 2; ++n) {
        float p0 = __builtin_exp2f(sacc[n][0]);
        float p1 = __builtin_exp2f(sacc[n][1]);
        float p2 = __builtin_exp2f(sacc[n][2]);
        float p3 = __builtin_exp2f(sacc[n][3]);
        ts += (p0 + p1) + (p2 + p3);
        bf16x4 pk;
        pk[0] = bfbits(p0); pk[1] = bfbits(p1); pk[2] = bfbits(p2); pk[3] = bfbits(p3);
        *reinterpret_cast<bf16x4*>(Pw + lr * 80 + n * 32 + lk * 8) = pk;
      }
      ts += __shfl_xor(ts, 16, 64);
      ts += __shfl_xor(ts, 32, 64);
      srow += ts;

      bf16x8 pa = *reinterpret_cast<const bf16x8*>(Pw + lr * 80 + lk * 16);

      __builtin_amdgcn_s_setprio(1);
#pragma unroll
      for (int n = 0; n < 4; ++n) {
        int rowp = n * 8 + (lr >> 1);
        int u = (lr & 1) * 4 + lk;
        int s = u ^ (rowp & 7);
        bf16x8 vf = *reinterpret_cast<const bf16x8*>(&Vbuf[buf][rowp * 64 + s * 8]);
        oacc[n] = __builtin_amdgcn_mfma_f32_16x16x32_bf16(vf, pa, oacc[n], 0, 0, 0);
      }
      __builtin_amdgcn_s_setprio(0);
    }

    __syncthreads();
    buf ^= 1;
  }

  const float inv = 1.0f / srow;
#pragma unroll
  for (int n = 0; n < 4; ++n) {
    bf16x4 pk;
#pragma unroll
    for (int r = 0; r < 4; ++r) pk[r] = bfbits(oacc[n][r] * inv);
    *reinterpret_cast<bf16x4*>(&ctx[((size_t)(bb * T_ + qrow)) * D_ + hh * DK_ + n * 16 + lk * 4]) = pk;
  }
}

// ---------------------------------------------------------------------------
// launch
// ---------------------------------------------------------------------------
extern "C" void kernel_launch(void* const* d_in, const int* in_sizes, int n_in,
                              void* d_out, int out_size, void* d_ws, size_t ws_size,
                              hipStream_t stream) {
  const float* q  = (const float*)d_in[0];
  const float* k  = (const float*)d_in[1];
  const float* v  = (const float*)d_in[2];
  const float* Wq = (const float*)d_in[3];
  const float* Wk = (const float*)d_in[4];
  const float* Wv = (const float*)d_in[5];
  const float* Wo = (const float*)d_in[6];
  const float* bq = (const float*)d_in[7];
  const float* bk = (const float*)d_in[8];
  const float* bv = (const float*)d_in[9];
  const float* bo = (const float*)d_in[10];

  constexpr size_t E_IN = (size_t)M_ * D_;
  constexpr size_t E_W  = (size_t)D_ * D_;
  char* ws = (char*)d_ws;
  size_t off = 0;
  bf16* qb  = (bf16*)(ws + off); off += E_IN * 2;
  bf16* kb  = (bf16*)(ws + off); off += E_IN * 2;
  bf16* vb  = (bf16*)(ws + off); off += E_IN * 2;
  bf16* Wqb = (bf16*)(ws + off); off += E_W * 2;
  bf16* Wkb = (bf16*)(ws + off); off += E_W * 2;
  bf16* Wvb = (bf16*)(ws + off); off += E_W * 2;
  bf16* Wob = (bf16*)(ws + off); off += E_W * 2;
  bf16* Qh  = (bf16*)(ws + off); off += E_IN * 2;
  bf16* Kh  = (bf16*)(ws + off); off += E_IN * 2;
  bf16* Vtw = (bf16*)(ws + off); off += E_IN * 2;
  bf16* ctx = (bf16*)(ws + off); off += E_IN * 2;

  cvt_all<<<dim3(28672), dim3(256), 0, stream>>>(q, k, v, Wq, Wk, Wv, Wo,
                                                 qb, kb, vb, Wqb, Wkb, Wvb, Wob);

  proj_qkv<<<dim3(32, 8, 3), dim3(512), 0, stream>>>(qb, kb, vb, Wqb, Wkb, Wvb,
                                                     bq, bk, bv, Qh, Kh, Vtw);

  attn_fwd<<<dim3(2048), dim3(256), 0, stream>>>(Qh, Kh, Vtw, ctx);

  gemm_out<<<dim3(32, 8), dim3(512), 0, stream>>>(ctx, Wob, bo, (float*)d_out);
}

// Round 14
// 203.891 us; speedup vs baseline: 1.2577x; 1.2577x over previous
//
#include <hip/hip_runtime.h>
#include <hip/hip_bf16.h>
#include <stdint.h>

#define B_ 4
#define T_ 2048
#define D_ 1024
#define H_ 16
#define DK_ 64
#define M_ (B_*T_)   // 8192

typedef __attribute__((ext_vector_type(8))) short bf16x8;
typedef __attribute__((ext_vector_type(4))) short bf16x4;
typedef __attribute__((ext_vector_type(4))) float f32x4;
typedef __hip_bfloat16 bf16;

__device__ __forceinline__ void gld_lds16(const bf16* g, bf16* l) {
  __builtin_amdgcn_global_load_lds((const __attribute__((address_space(1))) void*)g,
                                   (__attribute__((address_space(3))) void*)l,
                                   16, 0, 0);
}

__device__ __forceinline__ short bfbits(float f) {
  union { bf16 h; short s; } u; u.h = __float2bfloat16(f); return u.s;
}

// ---------------------------------------------------------------------------
// fused fp32 -> bf16 convert of all 7 tensors (round-8 exact)
// ---------------------------------------------------------------------------
__global__ __launch_bounds__(256) void cvt_all(
    const float* __restrict__ q, const float* __restrict__ k, const float* __restrict__ v,
    const float* __restrict__ wq, const float* __restrict__ wk,
    const float* __restrict__ wv, const float* __restrict__ wo,
    bf16* __restrict__ qb, bf16* __restrict__ kb, bf16* __restrict__ vb,
    bf16* __restrict__ wqb, bf16* __restrict__ wkb,
    bf16* __restrict__ wvb, bf16* __restrict__ wob) {
  int gid = blockIdx.x * 256 + threadIdx.x;   // 0 .. 7340031
  const float* src; bf16* dst; int off;
  if (gid < 6291456) {
    int s = gid >> 21; off = gid & 2097151;
    src = (s == 0) ? q : (s == 1) ? k : v;
    dst = (s == 0) ? qb : (s == 1) ? kb : vb;
  } else {
    int g2 = gid - 6291456;
    int s = g2 >> 18; off = g2 & 262143;
    src = (s == 0) ? wq : (s == 1) ? wk : (s == 2) ? wv : wo;
    dst = (s == 0) ? wqb : (s == 1) ? wkb : (s == 2) ? wvb : wob;
  }
  float4 val = reinterpret_cast<const float4*>(src)[off];
  union { ushort4 u; bf16 h[4]; } o;
  o.h[0] = __float2bfloat16(val.x);
  o.h[1] = __float2bfloat16(val.y);
  o.h[2] = __float2bfloat16(val.z);
  o.h[3] = __float2bfloat16(val.w);
  reinterpret_cast<ushort4*>(dst)[off] = o.u;
}

// ---------------------------------------------------------------------------
// Fused QKV projection v3: 256x128 tile, 512 threads, BK=32, DOUBLE-BUFFERED
// with EARLY-ISSUE staging (T3-minimum): stage(t+1) is issued right after the
// top-of-iter barrier and flies across the whole ds_read+MFMA phase; one
// __syncthreads per K-tile (drains the in-flight stage + protects buffers).
// LDS 48 KB -> 3 blocks/CU. Rows packed 2-per-128B LDS row with 8-slot XOR
// (attn-V pattern, conflict-free; roundtrip: stage u=s^(pr&7) <-> read
// u=(row&1)*4+lk).
// ---------------------------------------------------------------------------
__global__ __launch_bounds__(512) void proj_qkv(
    const bf16* __restrict__ qb, const bf16* __restrict__ kb, const bf16* __restrict__ vb,
    const bf16* __restrict__ Wqb, const bf16* __restrict__ Wkb, const bf16* __restrict__ Wvb,
    const float* __restrict__ bq, const float* __restrict__ bk, const float* __restrict__ bv,
    bf16* __restrict__ Qh, bf16* __restrict__ Kh, bf16* __restrict__ Vt) {
  constexpr int K = 1024;
  constexpr int BK = 32;
  constexpr int NT = K / BK;                  // 32
  __shared__ __align__(16) bf16 As[2][128 * 64];   // 2 x 16 KB (128 pairrows x 128B)
  __shared__ __align__(16) bf16 Bs[2][64 * 64];    // 2 x 8 KB  (64 pairrows)

  const int z = blockIdx.z;
  const bool vt = (z == 2);
  const bf16* A  = (z == 0) ? qb : (z == 1) ? kb : Wvb;
  const bf16* Bm = (z == 0) ? Wqb : (z == 1) ? Wkb : vb;
  const float* bias = (z == 0) ? bq : (z == 1) ? bk : bv;
  bf16* out = (z == 0) ? Qh : (z == 1) ? Kh : Vt;
  const float scale = (z == 0) ? 0.125f * 1.4426950408889634f : 1.0f;

  int bm, bn;
  if (vt) { int flat = blockIdx.x + 32 * blockIdx.y; bm = flat >> 6; bn = flat & 63; }
  else    { bm = blockIdx.x; bn = blockIdx.y; }

  const int tid = threadIdx.x;
  const int w = tid >> 6, l = tid & 63;
  const int wm = w >> 1, wn = w & 1;          // 4M x 2N wave grid
  const int lr = l & 15, lk = l >> 4;

  f32x4 acc[4][4] = {};

  // staging: packed layout, pre-swizzled global source, linear LDS dest
  auto stgA = [&](int t, int b) {
#pragma unroll
    for (int i = 0; i < 2; ++i) {
      int p16 = i * 512 + tid;                 // 1024 x 16B = 16 KB
      int pr = p16 >> 3, s = p16 & 7;
      int u = s ^ (pr & 7);
      int grow = pr * 2 + (u >> 2);
      gld_lds16(A + (size_t)(bm * 256 + grow) * K + t * BK + (u & 3) * 8,
                &As[b][p16 * 8]);
    }
  };
  auto stgB = [&](int t, int b) {
    int p16 = tid;                             // 512 x 16B = 8 KB
    int pr = p16 >> 3, s = p16 & 7;
    int u = s ^ (pr & 7);
    int grow = pr * 2 + (u >> 2);
    gld_lds16(Bm + (size_t)(bn * 128 + grow) * K + t * BK + (u & 3) * 8,
              &Bs[b][p16 * 8]);
  };

  stgA(0, 0); stgB(0, 0);                      // prologue

#pragma unroll 1
  for (int t = 0; t < NT; ++t) {
    __syncthreads();                           // drains stage(t); buffer safety
    if (t + 1 < NT) { stgA(t + 1, (t + 1) & 1); stgB(t + 1, (t + 1) & 1); }

    const int b = t & 1;
    bf16x8 af[4], bfr[4];
#pragma unroll
    for (int m = 0; m < 4; ++m) {
      int trow = wm * 64 + m * 16 + lr;
      int pr = trow >> 1;
      int u = (trow & 1) * 4 + lk;
      int s = u ^ (pr & 7);
      af[m] = *reinterpret_cast<const bf16x8*>(&As[b][(pr * 8 + s) * 8]);
    }
#pragma unroll
    for (int n = 0; n < 4; ++n) {
      int trow = wn * 64 + n * 16 + lr;
      int pr = trow >> 1;
      int u = (trow & 1) * 4 + lk;
      int s = u ^ (pr & 7);
      bfr[n] = *reinterpret_cast<const bf16x8*>(&Bs[b][(pr * 8 + s) * 8]);
    }
    __builtin_amdgcn_s_setprio(1);
#pragma unroll
    for (int m = 0; m < 4; ++m)
#pragma unroll
      for (int n = 0; n < 4; ++n)
        acc[m][n] = __builtin_amdgcn_mfma_f32_16x16x32_bf16(af[m], bfr[n], acc[m][n], 0, 0, 0);
    __builtin_amdgcn_s_setprio(0);
  }

  const int crow0 = bm * 256 + wm * 64;
  const int ccol0 = bn * 128 + wn * 64;
#pragma unroll
  for (int m = 0; m < 4; ++m) {
#pragma unroll
    for (int n = 0; n < 4; ++n) {
#pragma unroll
      for (int r = 0; r < 4; ++r) {
        const int row = crow0 + m * 16 + lk * 4 + r;
        const int col = ccol0 + n * 16 + lr;
        if (!vt) {
          float vv = (acc[m][n][r] + bias[col]) * scale;
          size_t idx = (((size_t)(row >> 11) * H_ + (col >> 6)) * T_ + (row & (T_ - 1))) * DK_ + (col & (DK_ - 1));
          out[idx] = __float2bfloat16(vv);
        } else {
          float vv = acc[m][n][r] + bias[row];
          size_t idx = (size_t)(col >> 11) * ((size_t)H_ * DK_ * T_) + (size_t)row * T_ + (col & (T_ - 1));
          out[idx] = __float2bfloat16(vv);
        }
      }
    }
  }
}

// ---------------------------------------------------------------------------
// Output GEMM v2 (fp32 out): same BK=32 dbuf early-issue structure.
// ---------------------------------------------------------------------------
__global__ __launch_bounds__(512) void gemm_out(const bf16* __restrict__ A,
                                                const bf16* __restrict__ Bm,
                                                const float* __restrict__ bias,
                                                float* __restrict__ Cout) {
  constexpr int K = 1024;
  constexpr int BK = 32;
  constexpr int NT = K / BK;
  __shared__ __align__(16) bf16 As[2][128 * 64];
  __shared__ __align__(16) bf16 Bs[2][64 * 64];

  const int bm = blockIdx.x;
  const int bn = blockIdx.y;
  const int tid = threadIdx.x;
  const int w = tid >> 6, l = tid & 63;
  const int wm = w >> 1, wn = w & 1;
  const int lr = l & 15, lk = l >> 4;

  f32x4 acc[4][4] = {};

  auto stgA = [&](int t, int b) {
#pragma unroll
    for (int i = 0; i < 2; ++i) {
      int p16 = i * 512 + tid;
      int pr = p16 >> 3, s = p16 & 7;
      int u = s ^ (pr & 7);
      int grow = pr * 2 + (u >> 2);
      gld_lds16(A + (size_t)(bm * 256 + grow) * K + t * BK + (u & 3) * 8,
                &As[b][p16 * 8]);
    }
  };
  auto stgB = [&](int t, int b) {
    int p16 = tid;
    int pr = p16 >> 3, s = p16 & 7;
    int u = s ^ (pr & 7);
    int grow = pr * 2 + (u >> 2);
    gld_lds16(Bm + (size_t)(bn * 128 + grow) * K + t * BK + (u & 3) * 8,
              &Bs[b][p16 * 8]);
  };

  stgA(0, 0); stgB(0, 0);

#pragma unroll 1
  for (int t = 0; t < NT; ++t) {
    __syncthreads();
    if (t + 1 < NT) { stgA(t + 1, (t + 1) & 1); stgB(t + 1, (t + 1) & 1); }

    const int b = t & 1;
    bf16x8 af[4], bfr[4];
#pragma unroll
    for (int m = 0; m < 4; ++m) {
      int trow = wm * 64 + m * 16 + lr;
      int pr = trow >> 1;
      int u = (trow & 1) * 4 + lk;
      int s = u ^ (pr & 7);
      af[m] = *reinterpret_cast<const bf16x8*>(&As[b][(pr * 8 + s) * 8]);
    }
#pragma unroll
    for (int n = 0; n < 4; ++n) {
      int trow = wn * 64 + n * 16 + lr;
      int pr = trow >> 1;
      int u = (trow & 1) * 4 + lk;
      int s = u ^ (pr & 7);
      bfr[n] = *reinterpret_cast<const bf16x8*>(&Bs[b][(pr * 8 + s) * 8]);
    }
    __builtin_amdgcn_s_setprio(1);
#pragma unroll
    for (int m = 0; m < 4; ++m)
#pragma unroll
      for (int n = 0; n < 4; ++n)
        acc[m][n] = __builtin_amdgcn_mfma_f32_16x16x32_bf16(af[m], bfr[n], acc[m][n], 0, 0, 0);
    __builtin_amdgcn_s_setprio(0);
  }

  const int crow0 = bm * 256 + wm * 64;
  const int ccol0 = bn * 128 + wn * 64;
#pragma unroll
  for (int m = 0; m < 4; ++m) {
#pragma unroll
    for (int n = 0; n < 4; ++n) {
#pragma unroll
      for (int r = 0; r < 4; ++r) {
        const int row = crow0 + m * 16 + lk * 4 + r;
        const int col = ccol0 + n * 16 + lr;
        Cout[(size_t)row * D_ + col] = acc[m][n][r] + bias[col];
      }
    }
  }
}

// ---------------------------------------------------------------------------
// Causal flash attention (round-12 exact): 7 blocks/CU, KVBLK=32,
// fixed-shift softmax, packed V, heavy-first single-task blocks.
// ---------------------------------------------------------------------------
__global__ __launch_bounds__(256, 7) void attn_fwd(const bf16* __restrict__ Qh,
                                                   const bf16* __restrict__ Kh,
                                                   const bf16* __restrict__ Vt,
                                                   bf16* __restrict__ ctx) {
  __shared__ __align__(16) bf16 Kbuf[2][32 * 64];
  __shared__ __align__(16) bf16 Vbuf[2][32 * 64];
  __shared__ __align__(16) char Ps[4][16 * 80];

  const int tid = threadIdx.x, w = tid >> 6, l = tid & 63;
  const int lr = l & 15, lk = l >> 4;
  const int bid = blockIdx.x;
  const int head = bid & 63;
  const int t = 31 - (bid >> 6);
  char* Pw = &Ps[w][0];

  const bf16* Qb = Qh + (size_t)head * T_ * DK_;
  const bf16* Kb = Kh + (size_t)head * T_ * DK_;
  const bf16* Vb = Vt + (size_t)head * DK_ * T_;
  const int bb = head >> 4, hh = head & 15;

  const int r0 = t * 64;
  const int nt32 = 2 * (t + 1);
  const int qrow = r0 + w * 16 + lr;
  const int jd = (r0 + w * 16) >> 5;

  const bf16* qp = Qb + (size_t)qrow * DK_ + lk * 8;
  bf16x8 qf0 = *reinterpret_cast<const bf16x8*>(qp);
  bf16x8 qf1 = *reinterpret_cast<const bf16x8*>(qp + 32);

  f32x4 oacc[4] = {};
  float srow = 0.f;

  {
    int p = tid;
    int krow = p >> 3;
    int kso = (p & 7) ^ (krow & 7);
    gld_lds16(Kb + (size_t)krow * DK_ + kso * 8, &Kbuf[0][p * 8]);
    int vrow = p >> 3;
    int u = (p & 7) ^ (vrow & 7);
    int dk = vrow * 2 + (u >> 2);
    gld_lds16(Vb + (size_t)dk * T_ + (u & 3) * 8, &Vbuf[0][p * 8]);
  }
  __syncthreads();

  int buf = 0;
#pragma unroll 1
  for (int j = 0; j < nt32; ++j) {
    if (j + 1 < nt32) {
      const int k0n = (j + 1) * 32;
      int p = tid;
      int krow = p >> 3;
      int kso = (p & 7) ^ (krow & 7);
      gld_lds16(Kb + (size_t)(k0n + krow) * DK_ + kso * 8, &Kbuf[buf ^ 1][p * 8]);
      int vrow = p >> 3;
      int u = (p & 7) ^ (vrow & 7);
      int dk = vrow * 2 + (u >> 2);
      gld_lds16(Vb + (size_t)dk * T_ + k0n + (u & 3) * 8, &Vbuf[buf ^ 1][p * 8]);
    }

    if (j <= jd) {
      f32x4 sacc[2] = {};
      __builtin_amdgcn_s_setprio(1);
#pragma unroll
      for (int n = 0; n < 2; ++n) {
        int row = n * 16 + lr;
        int s0 = lk ^ (row & 7);
        int s1 = (4 + lk) ^ (row & 7);
        bf16x8 kf0 = *reinterpret_cast<const bf16x8*>(&Kbuf[buf][row * 64 + s0 * 8]);
        bf16x8 kf1 = *reinterpret_cast<const bf16x8*>(&Kbuf[buf][row * 64 + s1 * 8]);
        sacc[n] = __builtin_amdgcn_mfma_f32_16x16x32_bf16(kf0, qf0, sacc[n], 0, 0, 0);
        sacc[n] = __builtin_amdgcn_mfma_f32_16x16x32_bf16(kf1, qf1, sacc[n], 0, 0, 0);
      }
      __builtin_amdgcn_s_setprio(0);

      if (j == jd) {
#pragma unroll
        for (int n = 0; n < 2; ++n)
#pragma unroll
          for (int r = 0; r < 4; ++r)
            if (j * 32 + n * 16 + lk * 4 + r > qrow) sacc[n][r] = -1e30f;
      }

      float ts = 0.f;
#pragma unroll
      for (int n = 0; n < 2; ++n) {
        float p0 = __builtin_exp2f(sacc[n][0]);
        float p1 = __builtin_exp2f(sacc[n][1]);
        float p2 = __builtin_exp2f(sacc[n][2]);
        float p3 = __builtin_exp2f(sacc[n][3]);
        ts += (p0 + p1) + (p2 + p3);
        bf16x4 pk;
        pk[0] = bfbits(p0); pk[1] = bfbits(p1); pk[2] = bfbits(p2); pk[3] = bfbits(p3);
        *reinterpret_cast<bf16x4*>(Pw + lr * 80 + n * 32 + lk * 8) = pk;
      }
      ts += __shfl_xor(ts, 16, 64);
      ts += __shfl_xor(ts, 32, 64);
      srow += ts;

      bf16x8 pa = *reinterpret_cast<const bf16x8*>(Pw + lr * 80 + lk * 16);

      __builtin_amdgcn_s_setprio(1);
#pragma unroll
      for (int n = 0; n < 4; ++n) {
        int rowp = n * 8 + (lr >> 1);
        int u = (lr & 1) * 4 + lk;
        int s = u ^ (rowp & 7);
        bf16x8 vf = *reinterpret_cast<const bf16x8*>(&Vbuf[buf][rowp * 64 + s * 8]);
        oacc[n] = __builtin_amdgcn_mfma_f32_16x16x32_bf16(vf, pa, oacc[n], 0, 0, 0);
      }
      __builtin_amdgcn_s_setprio(0);
    }

    __syncthreads();
    buf ^= 1;
  }

  const float inv = 1.0f / srow;
#pragma unroll
  for (int n = 0; n < 4; ++n) {
    bf16x4 pk;
#pragma unroll
    for (int r = 0; r < 4; ++r) pk[r] = bfbits(oacc[n][r] * inv);
    *reinterpret_cast<bf16x4*>(&ctx[((size_t)(bb * T_ + qrow)) * D_ + hh * DK_ + n * 16 + lk * 4]) = pk;
  }
}

// ---------------------------------------------------------------------------
// launch
// ---------------------------------------------------------------------------
extern "C" void kernel_launch(void* const* d_in, const int* in_sizes, int n_in,
                              void* d_out, int out_size, void* d_ws, size_t ws_size,
                              hipStream_t stream) {
  const float* q  = (const float*)d_in[0];
  const float* k  = (const float*)d_in[1];
  const float* v  = (const float*)d_in[2];
  const float* Wq = (const float*)d_in[3];
  const float* Wk = (const float*)d_in[4];
  const float* Wv = (const float*)d_in[5];
  const float* Wo = (const float*)d_in[6];
  const float* bq = (const float*)d_in[7];
  const float* bk = (const float*)d_in[8];
  const float* bv = (const float*)d_in[9];
  const float* bo = (const float*)d_in[10];

  constexpr size_t E_IN = (size_t)M_ * D_;
  constexpr size_t E_W  = (size_t)D_ * D_;
  char* ws = (char*)d_ws;
  size_t off = 0;
  bf16* qb  = (bf16*)(ws + off); off += E_IN * 2;
  bf16* kb  = (bf16*)(ws + off); off += E_IN * 2;
  bf16* vb  = (bf16*)(ws + off); off += E_IN * 2;
  bf16* Wqb = (bf16*)(ws + off); off += E_W * 2;
  bf16* Wkb = (bf16*)(ws + off); off += E_W * 2;
  bf16* Wvb = (bf16*)(ws + off); off += E_W * 2;
  bf16* Wob = (bf16*)(ws + off); off += E_W * 2;
  bf16* Qh  = (bf16*)(ws + off); off += E_IN * 2;
  bf16* Kh  = (bf16*)(ws + off); off += E_IN * 2;
  bf16* Vtw = (bf16*)(ws + off); off += E_IN * 2;
  bf16* ctx = (bf16*)(ws + off); off += E_IN * 2;

  cvt_all<<<dim3(28672), dim3(256), 0, stream>>>(q, k, v, Wq, Wk, Wv, Wo,
                                                 qb, kb, vb, Wqb, Wkb, Wvb, Wob);

  proj_qkv<<<dim3(32, 8, 3), dim3(512), 0, stream>>>(qb, kb, vb, Wqb, Wkb, Wvb,
                                                     bq, bk, bv, Qh, Kh, Vtw);

  attn_fwd<<<dim3(2048), dim3(256), 0, stream>>>(Qh, Kh, Vtw, ctx);

  gemm_out<<<dim3(32, 8), dim3(512), 0, stream>>>(ctx, Wob, bo, (float*)d_out);
}

// Round 15
// 191.610 us; speedup vs baseline: 1.3383x; 1.0641x over previous
//
#include <hip/hip_runtime.h>
#include <hip/hip_bf16.h>
#include <stdint.h>

#define B_ 4
#define T_ 2048
#define D_ 1024
#define H_ 16
#define DK_ 64
#define M_ (B_*T_)   // 8192

typedef __attribute__((ext_vector_type(8))) short bf16x8;
typedef __attribute__((ext_vector_type(4))) short bf16x4;
typedef __attribute__((ext_vector_type(4))) float f32x4;
typedef __hip_bfloat16 bf16;

__device__ __forceinline__ void gld_lds16(const bf16* g, bf16* l) {
  __builtin_amdgcn_global_load_lds((const __attribute__((address_space(1))) void*)g,
                                   (__attribute__((address_space(3))) void*)l,
                                   16, 0, 0);
}

__device__ __forceinline__ short bfbits(float f) {
  union { bf16 h; short s; } u; u.h = __float2bfloat16(f); return u.s;
}

// ---------------------------------------------------------------------------
// fused fp32 -> bf16 convert of all 7 tensors (round-8 exact)
// ---------------------------------------------------------------------------
__global__ __launch_bounds__(256) void cvt_all(
    const float* __restrict__ q, const float* __restrict__ k, const float* __restrict__ v,
    const float* __restrict__ wq, const float* __restrict__ wk,
    const float* __restrict__ wv, const float* __restrict__ wo,
    bf16* __restrict__ qb, bf16* __restrict__ kb, bf16* __restrict__ vb,
    bf16* __restrict__ wqb, bf16* __restrict__ wkb,
    bf16* __restrict__ wvb, bf16* __restrict__ wob) {
  int gid = blockIdx.x * 256 + threadIdx.x;   // 0 .. 7340031
  const float* src; bf16* dst; int off;
  if (gid < 6291456) {
    int s = gid >> 21; off = gid & 2097151;
    src = (s == 0) ? q : (s == 1) ? k : v;
    dst = (s == 0) ? qb : (s == 1) ? kb : vb;
  } else {
    int g2 = gid - 6291456;
    int s = g2 >> 18; off = g2 & 262143;
    src = (s == 0) ? wq : (s == 1) ? wk : (s == 2) ? wv : wo;
    dst = (s == 0) ? wqb : (s == 1) ? wkb : (s == 2) ? wvb : wob;
  }
  float4 val = reinterpret_cast<const float4*>(src)[off];
  union { ushort4 u; bf16 h[4]; } o;
  o.h[0] = __float2bfloat16(val.x);
  o.h[1] = __float2bfloat16(val.y);
  o.h[2] = __float2bfloat16(val.z);
  o.h[3] = __float2bfloat16(val.w);
  reinterpret_cast<ushort4*>(dst)[off] = o.u;
}

// ---------------------------------------------------------------------------
// Fused QKV projection GEMM, 256x128 tile, 512 threads (round-12 structure)
// + XCD-aware block remap for z<2: xcd = bid&7 owns bm in [xcd*4, xcd*4+4)
// -> per-XCD A-panel working set = 2 MB (L2-resident), A re-reads become
// L2 hits instead of L3. z=2 (Wv side) unchanged: Wv is 2 MB total already.
// ---------------------------------------------------------------------------
__global__ __launch_bounds__(512) void proj_qkv(
    const bf16* __restrict__ qb, const bf16* __restrict__ kb, const bf16* __restrict__ vb,
    const bf16* __restrict__ Wqb, const bf16* __restrict__ Wkb, const bf16* __restrict__ Wvb,
    const float* __restrict__ bq, const float* __restrict__ bk, const float* __restrict__ bv,
    bf16* __restrict__ Qh, bf16* __restrict__ Kh, bf16* __restrict__ Vt) {
  constexpr int K = 1024;
  constexpr int BK = 64;
  __shared__ __align__(16) bf16 As[256 * BK];
  __shared__ __align__(16) bf16 Bs[128 * BK];

  const int z = blockIdx.z;
  const bool vt = (z == 2);
  const bf16* A  = (z == 0) ? qb : (z == 1) ? kb : Wvb;
  const bf16* Bm = (z == 0) ? Wqb : (z == 1) ? Wkb : vb;
  const float* bias = (z == 0) ? bq : (z == 1) ? bk : bv;
  bf16* out = (z == 0) ? Qh : (z == 1) ? Kh : Vt;
  const float scale = (z == 0) ? 0.125f * 1.4426950408889634f : 1.0f;

  const int bid = blockIdx.x + 32 * blockIdx.y;   // 0..255
  int bm, bn;
  if (vt) {
    bm = bid >> 6; bn = bid & 63;                 // Wv tiny: any order fine
  } else {
    const int xcd = bid & 7, loc = bid >> 3;      // XCD-pinned A panels
    bm = xcd * 4 + (loc & 3);                     // bijective: 8*4*8 = 256
    bn = loc >> 2;
  }

  const int tid = threadIdx.x;
  const int w = tid >> 6, l = tid & 63;
  const int wm = w >> 1, wn = w & 1;
  const int lr = l & 15, lk = l >> 4;

  f32x4 acc[4][4] = {};

  for (int k0 = 0; k0 < K; k0 += BK) {
#pragma unroll
    for (int i = 0; i < 4; ++i) {
      int p = i * 512 + tid;
      int row = p >> 3;
      int so = (p & 7) ^ (row & 7);
      gld_lds16(A + (size_t)(bm * 256 + row) * K + k0 + so * 8, &As[p * 8]);
    }
#pragma unroll
    for (int i = 0; i < 2; ++i) {
      int p = i * 512 + tid;
      int row = p >> 3;
      int so = (p & 7) ^ (row & 7);
      gld_lds16(Bm + (size_t)(bn * 128 + row) * K + k0 + so * 8, &Bs[p * 8]);
    }
    __syncthreads();

#pragma unroll
    for (int kk = 0; kk < 2; ++kk) {
      bf16x8 af[4], bfr[4];
#pragma unroll
      for (int m = 0; m < 4; ++m) {
        int row = wm * 64 + m * 16 + lr;
        int slot = (kk * 4 + lk) ^ (row & 7);
        af[m] = *reinterpret_cast<const bf16x8*>(&As[row * BK + slot * 8]);
      }
#pragma unroll
      for (int n = 0; n < 4; ++n) {
        int row = wn * 64 + n * 16 + lr;
        int slot = (kk * 4 + lk) ^ (row & 7);
        bfr[n] = *reinterpret_cast<const bf16x8*>(&Bs[row * BK + slot * 8]);
      }
#pragma unroll
      for (int m = 0; m < 4; ++m)
#pragma unroll
        for (int n = 0; n < 4; ++n)
          acc[m][n] = __builtin_amdgcn_mfma_f32_16x16x32_bf16(af[m], bfr[n], acc[m][n], 0, 0, 0);
    }
    __syncthreads();
  }

  const int crow0 = bm * 256 + wm * 64;
  const int ccol0 = bn * 128 + wn * 64;
#pragma unroll
  for (int m = 0; m < 4; ++m) {
#pragma unroll
    for (int n = 0; n < 4; ++n) {
#pragma unroll
      for (int r = 0; r < 4; ++r) {
        const int row = crow0 + m * 16 + lk * 4 + r;
        const int col = ccol0 + n * 16 + lr;
        if (!vt) {
          float vv = (acc[m][n][r] + bias[col]) * scale;
          size_t idx = (((size_t)(row >> 11) * H_ + (col >> 6)) * T_ + (row & (T_ - 1))) * DK_ + (col & (DK_ - 1));
          out[idx] = __float2bfloat16(vv);
        } else {
          float vv = acc[m][n][r] + bias[row];
          size_t idx = (size_t)(col >> 11) * ((size_t)H_ * DK_ * T_) + (size_t)row * T_ + (col & (T_ - 1));
          out[idx] = __float2bfloat16(vv);
        }
      }
    }
  }
}

// ---------------------------------------------------------------------------
// Output GEMM (fp32 out), 256x128 tile, 512 threads (round-8 structure)
// + same XCD-aware remap (A = ctx panels pinned per XCD).
// ---------------------------------------------------------------------------
__global__ __launch_bounds__(512) void gemm_out(const bf16* __restrict__ A,
                                                const bf16* __restrict__ Bm,
                                                const float* __restrict__ bias,
                                                float* __restrict__ Cout) {
  constexpr int K = 1024;
  constexpr int BK = 64;
  __shared__ __align__(16) bf16 As[256 * BK];
  __shared__ __align__(16) bf16 Bs[128 * BK];

  const int bid = blockIdx.x + 32 * blockIdx.y;   // 0..255
  const int xcd = bid & 7, loc = bid >> 3;
  const int bm = xcd * 4 + (loc & 3);
  const int bn = loc >> 2;

  const int tid = threadIdx.x;
  const int w = tid >> 6, l = tid & 63;
  const int wm = w >> 1, wn = w & 1;
  const int lr = l & 15, lk = l >> 4;

  f32x4 acc[4][4] = {};

  for (int k0 = 0; k0 < K; k0 += BK) {
#pragma unroll
    for (int i = 0; i < 4; ++i) {
      int p = i * 512 + tid;
      int row = p >> 3;
      int so = (p & 7) ^ (row & 7);
      gld_lds16(A + (size_t)(bm * 256 + row) * K + k0 + so * 8, &As[p * 8]);
    }
#pragma unroll
    for (int i = 0; i < 2; ++i) {
      int p = i * 512 + tid;
      int row = p >> 3;
      int so = (p & 7) ^ (row & 7);
      gld_lds16(Bm + (size_t)(bn * 128 + row) * K + k0 + so * 8, &Bs[p * 8]);
    }
    __syncthreads();

#pragma unroll
    for (int kk = 0; kk < 2; ++kk) {
      bf16x8 af[4], bfr[4];
#pragma unroll
      for (int m = 0; m < 4; ++m) {
        int row = wm * 64 + m * 16 + lr;
        int slot = (kk * 4 + lk) ^ (row & 7);
        af[m] = *reinterpret_cast<const bf16x8*>(&As[row * BK + slot * 8]);
      }
#pragma unroll
      for (int n = 0; n < 4; ++n) {
        int row = wn * 64 + n * 16 + lr;
        int slot = (kk * 4 + lk) ^ (row & 7);
        bfr[n] = *reinterpret_cast<const bf16x8*>(&Bs[row * BK + slot * 8]);
      }
#pragma unroll
      for (int m = 0; m < 4; ++m)
#pragma unroll
        for (int n = 0; n < 4; ++n)
          acc[m][n] = __builtin_amdgcn_mfma_f32_16x16x32_bf16(af[m], bfr[n], acc[m][n], 0, 0, 0);
    }
    __syncthreads();
  }

  const int crow0 = bm * 256 + wm * 64;
  const int ccol0 = bn * 128 + wn * 64;
#pragma unroll
  for (int m = 0; m < 4; ++m) {
#pragma unroll
    for (int n = 0; n < 4; ++n) {
#pragma unroll
      for (int r = 0; r < 4; ++r) {
        const int row = crow0 + m * 16 + lk * 4 + r;
        const int col = ccol0 + n * 16 + lr;
        Cout[(size_t)row * D_ + col] = acc[m][n][r] + bias[col];
      }
    }
  }
}

// ---------------------------------------------------------------------------
// Causal flash attention (round-12 exact): 7 blocks/CU, KVBLK=32,
// fixed-shift softmax, packed V, heavy-first single-task blocks.
// ---------------------------------------------------------------------------
__global__ __launch_bounds__(256, 7) void attn_fwd(const bf16* __restrict__ Qh,
                                                   const bf16* __restrict__ Kh,
                                                   const bf16* __restrict__ Vt,
                                                   bf16* __restrict__ ctx) {
  __shared__ __align__(16) bf16 Kbuf[2][32 * 64];
  __shared__ __align__(16) bf16 Vbuf[2][32 * 64];
  __shared__ __align__(16) char Ps[4][16 * 80];

  const int tid = threadIdx.x, w = tid >> 6, l = tid & 63;
  const int lr = l & 15, lk = l >> 4;
  const int bid = blockIdx.x;
  const int head = bid & 63;
  const int t = 31 - (bid >> 6);
  char* Pw = &Ps[w][0];

  const bf16* Qb = Qh + (size_t)head * T_ * DK_;
  const bf16* Kb = Kh + (size_t)head * T_ * DK_;
  const bf16* Vb = Vt + (size_t)head * DK_ * T_;
  const int bb = head >> 4, hh = head & 15;

  const int r0 = t * 64;
  const int nt32 = 2 * (t + 1);
  const int qrow = r0 + w * 16 + lr;
  const int jd = (r0 + w * 16) >> 5;

  const bf16* qp = Qb + (size_t)qrow * DK_ + lk * 8;
  bf16x8 qf0 = *reinterpret_cast<const bf16x8*>(qp);
  bf16x8 qf1 = *reinterpret_cast<const bf16x8*>(qp + 32);

  f32x4 oacc[4] = {};
  float srow = 0.f;

  {
    int p = tid;
    int krow = p >> 3;
    int kso = (p & 7) ^ (krow & 7);
    gld_lds16(Kb + (size_t)krow * DK_ + kso * 8, &Kbuf[0][p * 8]);
    int vrow = p >> 3;
    int u = (p & 7) ^ (vrow & 7);
    int dk = vrow * 2 + (u >> 2);
    gld_lds16(Vb + (size_t)dk * T_ + (u & 3) * 8, &Vbuf[0][p * 8]);
  }
  __syncthreads();

  int buf = 0;
#pragma unroll 1
  for (int j = 0; j < nt32; ++j) {
    if (j + 1 < nt32) {
      const int k0n = (j + 1) * 32;
      int p = tid;
      int krow = p >> 3;
      int kso = (p & 7) ^ (krow & 7);
      gld_lds16(Kb + (size_t)(k0n + krow) * DK_ + kso * 8, &Kbuf[buf ^ 1][p * 8]);
      int vrow = p >> 3;
      int u = (p & 7) ^ (vrow & 7);
      int dk = vrow * 2 + (u >> 2);
      gld_lds16(Vb + (size_t)dk * T_ + k0n + (u & 3) * 8, &Vbuf[buf ^ 1][p * 8]);
    }

    if (j <= jd) {
      f32x4 sacc[2] = {};
      __builtin_amdgcn_s_setprio(1);
#pragma unroll
      for (int n = 0; n < 2; ++n) {
        int row = n * 16 + lr;
        int s0 = lk ^ (row & 7);
        int s1 = (4 + lk) ^ (row & 7);
        bf16x8 kf0 = *reinterpret_cast<const bf16x8*>(&Kbuf[buf][row * 64 + s0 * 8]);
        bf16x8 kf1 = *reinterpret_cast<const bf16x8*>(&Kbuf[buf][row * 64 + s1 * 8]);
        sacc[n] = __builtin_amdgcn_mfma_f32_16x16x32_bf16(kf0, qf0, sacc[n], 0, 0, 0);
        sacc[n] = __builtin_amdgcn_mfma_f32_16x16x32_bf16(kf1, qf1, sacc[n], 0, 0, 0);
      }
      __builtin_amdgcn_s_setprio(0);

      if (j == jd) {
#pragma unroll
        for (int n = 0; n < 2; ++n)
#pragma unroll
          for (int r = 0; r < 4; ++r)
            if (j * 32 + n * 16 + lk * 4 + r > qrow) sacc[n][r] = -1e30f;
      }

      float ts = 0.f;
#pragma unroll
      for (int n = 0; n < 2; ++n) {
        float p0 = __builtin_exp2f(sacc[n][0]);
        float p1 = __builtin_exp2f(sacc[n][1]);
        float p2 = __builtin_exp2f(sacc[n][2]);
        float p3 = __builtin_exp2f(sacc[n][3]);
        ts += (p0 + p1) + (p2 + p3);
        bf16x4 pk;
        pk[0] = bfbits(p0); pk[1] = bfbits(p1); pk[2] = bfbits(p2); pk[3] = bfbits(p3);
        *reinterpret_cast<bf16x4*>(Pw + lr * 80 + n * 32 + lk * 8) = pk;
      }
      ts += __shfl_xor(ts, 16, 64);
      ts += __shfl_xor(ts, 32, 64);
      srow += ts;

      bf16x8 pa = *reinterpret_cast<const bf16x8*>(Pw + lr * 80 + lk * 16);

      __builtin_amdgcn_s_setprio(1);
#pragma unroll
      for (int n = 0; n < 4; ++n) {
        int rowp = n * 8 + (lr >> 1);
        int u = (lr & 1) * 4 + lk;
        int s = u ^ (rowp & 7);
        bf16x8 vf = *reinterpret_cast<const bf16x8*>(&Vbuf[buf][rowp * 64 + s * 8]);
        oacc[n] = __builtin_amdgcn_mfma_f32_16x16x32_bf16(vf, pa, oacc[n], 0, 0, 0);
      }
      __builtin_amdgcn_s_setprio(0);
    }

    __syncthreads();
    buf ^= 1;
  }

  const float inv = 1.0f / srow;
#pragma unroll
  for (int n = 0; n < 4; ++n) {
    bf16x4 pk;
#pragma unroll
    for (int r = 0; r < 4; ++r) pk[r] = bfbits(oacc[n][r] * inv);
    *reinterpret_cast<bf16x4*>(&ctx[((size_t)(bb * T_ + qrow)) * D_ + hh * DK_ + n * 16 + lk * 4]) = pk;
  }
}

// ---------------------------------------------------------------------------
// launch
// ---------------------------------------------------------------------------
extern "C" void kernel_launch(void* const* d_in, const int* in_sizes, int n_in,
                              void* d_out, int out_size, void* d_ws, size_t ws_size,
                              hipStream_t stream) {
  const float* q  = (const float*)d_in[0];
  const float* k  = (const float*)d_in[1];
  const float* v  = (const float*)d_in[2];
  const float* Wq = (const float*)d_in[3];
  const float* Wk = (const float*)d_in[4];
  const float* Wv = (const float*)d_in[5];
  const float* Wo = (const float*)d_in[6];
  const float* bq = (const float*)d_in[7];
  const float* bk = (const float*)d_in[8];
  const float* bv = (const float*)d_in[9];
  const float* bo = (const float*)d_in[10];

  constexpr size_t E_IN = (size_t)M_ * D_;
  constexpr size_t E_W  = (size_t)D_ * D_;
  char* ws = (char*)d_ws;
  size_t off = 0;
  bf16* qb  = (bf16*)(ws + off); off += E_IN * 2;
  bf16* kb  = (bf16*)(ws + off); off += E_IN * 2;
  bf16* vb  = (bf16*)(ws + off); off += E_IN * 2;
  bf16* Wqb = (bf16*)(ws + off); off += E_W * 2;
  bf16* Wkb = (bf16*)(ws + off); off += E_W * 2;
  bf16* Wvb = (bf16*)(ws + off); off += E_W * 2;
  bf16* Wob = (bf16*)(ws + off); off += E_W * 2;
  bf16* Qh  = (bf16*)(ws + off); off += E_IN * 2;
  bf16* Kh  = (bf16*)(ws + off); off += E_IN * 2;
  bf16* Vtw = (bf16*)(ws + off); off += E_IN * 2;
  bf16* ctx = (bf16*)(ws + off); off += E_IN * 2;

  cvt_all<<<dim3(28672), dim3(256), 0, stream>>>(q, k, v, Wq, Wk, Wv, Wo,
                                                 qb, kb, vb, Wqb, Wkb, Wvb, Wob);

  proj_qkv<<<dim3(32, 8, 3), dim3(512), 0, stream>>>(qb, kb, vb, Wqb, Wkb, Wvb,
                                                     bq, bk, bv, Qh, Kh, Vtw);

  attn_fwd<<<dim3(2048), dim3(256), 0, stream>>>(Qh, Kh, Vtw, ctx);

  gemm_out<<<dim3(32, 8), dim3(512), 0, stream>>>(ctx, Wob, bo, (float*)d_out);
}